// Round 14
// baseline (347.334 us; speedup 1.0000x reference)
//
#include <hip/hip_runtime.h>

#define BB     256
#define TT     2048
#define DIN    10
#define UU     64
#define DOUT   2
#define CHUNK  64
#define NCHUNK (TT / CHUNK)
#define HISTP  68   // mult of 4 -> 16B-aligned b128 quarter reads

typedef float f32x2 __attribute__((ext_vector_type(2)));
typedef float f32x4 __attribute__((ext_vector_type(4)));

// 2*log2(e): recurrence tracked as u = 1/(exp2(C*z)+1), h = 1-2u = tanh(z)
#define CSCALE 2.8853900817779268f

#if __has_builtin(__builtin_elementwise_fma)
__device__ __forceinline__ f32x2 pkfma(f32x2 a, f32x2 b, f32x2 c) {
    return __builtin_elementwise_fma(a, b, c);
}
#else
__device__ __forceinline__ f32x2 pkfma(f32x2 a, f32x2 b, f32x2 c) {
    f32x2 r; r.x = fmaf(a.x, b.x, c.x); r.y = fmaf(a.y, b.y, c.y); return r;
}
#endif

// row_ror:D DPP (within each 16-lane row), on a float reg
template <int D>
__device__ __forceinline__ float rordpp(float v) {
    return __int_as_float(
        __builtin_amdgcn_mov_dpp(__float_as_int(v), 0x120 + D, 0xF, 0xF, false));
}
template <int D>
__device__ __forceinline__ f32x2 rordpp2(f32x2 v) {
    f32x2 r; r.x = rordpp<D>(v.x); r.y = rordpp<D>(v.y); return r;
}

__global__ __launch_bounds__(128) void rnn_scan_kernel(
    const float* __restrict__ x,    // [B,T,DIN]
    const float* __restrict__ Wx,   // [DIN,U]
    const float* __restrict__ Wh,   // [U,U]
    const float* __restrict__ bias, // [U]
    const float* __restrict__ Wd,   // [U,DOUT]
    const float* __restrict__ bd,   // [DOUT]
    float* __restrict__ out)        // [B,T,DOUT]
{
    // Wave 0 (consumer): recurrence. Handoff = hist row write -> ONE b128 read
    // (lane covers only k = 4r..4r+3). Cross-lane reduce = circulant row_ror
    // tree, pure VALU (no DS hops on the chain).
    // Wave 1 (producer): x-projection c+1, Dense c-1.  (R6/R13 structure.)
    __shared__ float xps[2][CHUNK * UU];                    // C*(b+x@Wx+sumWh)
    __shared__ __align__(16) float hist[2][CHUNK * HISTP];  // u history = state
    __shared__ __align__(16) float xs[CHUNK * 12];
    __shared__ __align__(8)  f32x2 wdl2[UU];                // -2*Wd rows

    const int tid = threadIdx.x;
    const int wid = tid >> 6;    // 0 = scan wave, 1 = producer wave
    const int l   = tid & 63;
    const int b   = blockIdx.x;
    const int q   = l >> 4;      // row
    const int r   = l & 15;      // lane within row; k-slice = 4r..4r+3

    // --- probe DPP row_ror direction delta (init-only; used ONLY for the
    //     weight unit mapping — the tree's slot algebra is delta-invariant) ---
    int dstep;
    {
        int p = __builtin_amdgcn_mov_dpp(r, 0x121, 0xF, 0xF, false);
        dstep = (p - r) & 15;    // 1 or 15 (= -1 mod 16)
    }

    // --- Wh fragments, scaled: W2'[k,c] = -2*C*Wh[k,c].
    //     Slot j of lane (q,r): unit 16q + ((r + dstep*(j-7)) & 15), k-slice 4r..4r+3.
    //     Packed pairs: w2[t][i] = (slot 2t, slot 2t+1) at k = 4r+i.
    f32x2 w2[8][4];
#pragma unroll
    for (int t = 0; t < 8; ++t) {
        const int cA = 16 * q + ((r + dstep * ((2 * t + 9) & 15)) & 15);  // j-7 == j+9 mod 16
        const int cB = 16 * q + ((r + dstep * ((2 * t + 10) & 15)) & 15);
#pragma unroll
        for (int i = 0; i < 4; ++i) {
            const int k = 4 * r + i;
            f32x2 w;
            w.x = -2.0f * CSCALE * Wh[(size_t)k * UU + cA];
            w.y = -2.0f * CSCALE * Wh[(size_t)k * UU + cB];
            w2[t][i] = w;
        }
    }

    // --- producer-wave constants ---
    f32x2 wxp[5];
#pragma unroll
    for (int d2 = 0; d2 < 5; ++d2) {
        f32x2 w;
        w.x = CSCALE * Wx[(2 * d2) * UU + l];
        w.y = CSCALE * Wx[(2 * d2 + 1) * UU + l];
        wxp[d2] = w;
    }
    float Kl;
    {
        float s = bias[l];
        for (int k = 0; k < UU; ++k) s += Wh[(size_t)k * UU + l];
        Kl = CSCALE * s;
    }
    f32x2 bdd;
    {
        float s0 = bd[0], s1 = bd[1];
        for (int k = 0; k < UU; ++k) { s0 += Wd[k * DOUT + 0]; s1 += Wd[k * DOUT + 1]; }
        bdd.x = s0; bdd.y = s1;
    }

    float* prev = &hist[1][63 * HISTP];   // scan state pointer (prev u row)
    if (wid == 0) {
        f32x2 w; w.x = -2.0f * Wd[l * DOUT + 0]; w.y = -2.0f * Wd[l * DOUT + 1];
        wdl2[l] = w;
        prev[l] = 0.5f;                   // h_0 = 0  (u = 0.5)
    }

    const float* xb = x + (size_t)b * TT * DIN;
    float*       ob = out + (size_t)b * TT * DOUT;

    // --- producer helpers (unchanged) ---
    auto fill_xps = [&](int cn) {
        const f32x2* xr = (const f32x2*)(xb + (size_t)(cn * CHUNK + l) * DIN);
        f32x2 v0 = xr[0], v1 = xr[1], v2 = xr[2], v3 = xr[3], v4 = xr[4];
        f32x2* dst = (f32x2*)&xs[l * 12];
        dst[0] = v0; dst[1] = v1; dst[2] = v2; dst[3] = v3; dst[4] = v4;
        float* xp_out = &xps[cn & 1][l];
#pragma unroll 4
        for (int s = 0; s < CHUNK; ++s) {
            const float* p = &xs[s * 12];
            f32x4 xa = ((const f32x4*)p)[0];
            f32x4 xc = ((const f32x4*)p)[1];
            f32x2 xe = ((const f32x2*)p)[4];
            f32x2 acc = {Kl, 0.0f};
            acc = pkfma(__builtin_shufflevector(xa, xa, 0, 1), wxp[0], acc);
            acc = pkfma(__builtin_shufflevector(xa, xa, 2, 3), wxp[1], acc);
            acc = pkfma(__builtin_shufflevector(xc, xc, 0, 1), wxp[2], acc);
            acc = pkfma(__builtin_shufflevector(xc, xc, 2, 3), wxp[3], acc);
            acc = pkfma(xe, wxp[4], acc);
            xp_out[s * UU] = acc.x + acc.y;
        }
    };
    auto dense_chunk = [&](int cd) {
        const float* hrow = &hist[cd & 1][l * HISTP];
        f32x2 acc = bdd;
#pragma unroll 8
        for (int k = 0; k < UU; ++k) {
            float u = hrow[k];
            f32x2 uu; uu.x = u; uu.y = u;
            acc = pkfma(uu, wdl2[k], acc);
        }
        float2 o; o.x = acc.x; o.y = acc.y;
        *(float2*)(ob + (size_t)(cd * CHUNK + l) * DOUT) = o;
    };

    // prologue: producer fills chunk 0's x-projection
    if (wid == 1) fill_xps(0);
    __syncthreads();

    // --- scan: 1 b128 handoff read + 32 pk_fma (depth 4) + row_ror tree ---
    auto scan_chunk = [&](int c) {
        const float* xpsrc = &xps[c & 1][l];
        float* hbuf = &hist[c & 1][0];
#pragma unroll 8
        for (int s = 0; s < CHUNK; ++s) {
            float xpv = xpsrc[s * UU];           // independent -> hoistable
            // handoff read: this lane's 4 h-slice (16 addrs wave-wide, 2-way alias)
            f32x4 hq = *(const f32x4*)(prev + 4 * r);
            // dot: 16 slots x 4 k, packed as 8 f32x2 accumulators, depth 4
            f32x2 P[8];
            {
                f32x2 h0; h0.x = hq.x; h0.y = hq.x;
                f32x2 h1; h1.x = hq.y; h1.y = hq.y;
                f32x2 h2; h2.x = hq.z; h2.y = hq.z;
                f32x2 h3; h3.x = hq.w; h3.y = hq.w;
#pragma unroll
                for (int t = 0; t < 8; ++t) {
                    f32x2 a = h0 * w2[t][0];
                    a = pkfma(h1, w2[t][1], a);
                    a = pkfma(h2, w2[t][2], a);
                    a = pkfma(h3, w2[t][3], a);
                    P[t] = a;
                }
            }
            // circulant row_ror reduce tree (delta-invariant slot algebra):
            // stage d=8: Q[j] = P[j] + ror8(P[j+8]), j = 0..7
            f32x2 Q0 = P[0] + rordpp2<8>(P[4]);
            f32x2 Q1 = P[1] + rordpp2<8>(P[5]);
            f32x2 Q2 = P[2] + rordpp2<8>(P[6]);
            f32x2 Q3 = P[3] + rordpp2<8>(P[7]);
            // stage d=4: T[j] = Q[j] + ror4(Q[j-4]), j = 4..7
            f32x2 T2 = Q2 + rordpp2<4>(Q0);
            f32x2 T3 = Q3 + rordpp2<4>(Q1);
            // stage d=2: S[j] = T[j] + ror2(T[j-2]), j = 6..7
            f32x2 S = T3 + rordpp2<2>(T2);
            // stage d=1: z = S[7] + ror1(S[6])  -> unit l lands on lane l
            float zr = S.y + rordpp<1>(S.x);
            float zp = zr + xpv;                 // = C*z
#if __has_builtin(__builtin_amdgcn_exp2f)
            float e = __builtin_amdgcn_exp2f(zp);
#else
            float e = exp2f(zp);
#endif
            float u = __builtin_amdgcn_rcpf(e + 1.0f);  // h = 1-2u
            float* hrow = hbuf + s * HISTP;
            hrow[l] = u;                         // state handoff AND hist
            prev = hrow;
        }
    };

    for (int c = 0; c < NCHUNK; ++c) {
        if (wid == 0) {
            scan_chunk(c);
        } else {
            if (c + 1 < NCHUNK) fill_xps(c + 1);
            if (c > 0)          dense_chunk(c - 1);
        }
        __syncthreads();
    }
    if (wid == 1) dense_chunk(NCHUNK - 1);
}

extern "C" void kernel_launch(void* const* d_in, const int* in_sizes, int n_in,
                              void* d_out, int out_size, void* d_ws, size_t ws_size,
                              hipStream_t stream) {
    const float* x    = (const float*)d_in[0];
    const float* Wx   = (const float*)d_in[1];
    const float* Wh   = (const float*)d_in[2];
    const float* bias = (const float*)d_in[3];
    const float* Wd   = (const float*)d_in[4];
    const float* bd   = (const float*)d_in[5];
    float* out = (float*)d_out;

    rnn_scan_kernel<<<BB, 128, 0, stream>>>(x, Wx, Wh, bias, Wd, bd, out);
}